// Round 16
// baseline (142.112 us; speedup 1.0000x reference)
//
#include <hip/hip_runtime.h>

#define FDIM  256
#define H1D   256
#define H2D   128
#define BATCH 4096

typedef _Float16 half2v __attribute__((ext_vector_type(2)));

#define ROW_U16   258                       // 128 A + 128 C + 2 pad (129 u32)
#define ROWS_PER_F 257
#define ROWS_BYTES ((size_t)FDIM * ROWS_PER_F * ROW_U16 * 2)   // 33,948,672
#define XT_BYTES   ((size_t)FDIM * BATCH * 4)                  //  4,194,304
#define TS_BYTES   ((size_t)FDIM * H1D * 4)                    //    262,144
#define W3H_BYTES  ((size_t)FDIM * 64 * 4)                     //     65,536
#define LDS_U32    (ROWS_PER_F * 129)                          //     33,153
#define LDS_BYTES  (LDS_U32 * 4 + 256 * 4)                     //    133,636

union U32H2 { unsigned u; half2v h; };

// ---------------------------------------------------------------------------
// prep2: [0,256): x (B,F) f32 -> xT (F,B) f32 transpose.
//        [256,320): W3 f32 -> f16-pair packed w3h[f][64].
// ---------------------------------------------------------------------------
__global__ __launch_bounds__(256) void prep2(const float* __restrict__ x,
                                             const float* __restrict__ W3,
                                             float* __restrict__ xT,
                                             unsigned* __restrict__ w3h) {
    const int bid = blockIdx.x, tid = threadIdx.x;
    if (bid < 256) {
        __shared__ float tile[64][65];
        const int bt = bid >> 2, ft = bid & 3;
        const int tr = tid >> 2, c0 = (tid & 3) * 16;
#pragma unroll
        for (int j = 0; j < 4; ++j) {
            const float4 v = *(const float4*)(
                x + (size_t)(bt * 64 + tr) * FDIM + ft * 64 + c0 + j * 4);
            tile[tr][c0 + j * 4 + 0] = v.x;
            tile[tr][c0 + j * 4 + 1] = v.y;
            tile[tr][c0 + j * 4 + 2] = v.z;
            tile[tr][c0 + j * 4 + 3] = v.w;
        }
        __syncthreads();
        const int fr = tid >> 2, bb = (tid & 3) * 16;
#pragma unroll
        for (int j = 0; j < 4; ++j) {
            float4 o;
            o.x = tile[bb + j * 4 + 0][fr];
            o.y = tile[bb + j * 4 + 1][fr];
            o.z = tile[bb + j * 4 + 2][fr];
            o.w = tile[bb + j * 4 + 3][fr];
            *(float4*)(xT + (size_t)(ft * 64 + fr) * BATCH + bt * 64 + bb + j * 4) = o;
        }
    } else {
        const int idx = (bid - 256) * 256 + tid;    // 0..16383
        const int f = idx >> 6, p = idx & 63;
        const _Float16 a = (_Float16)W3[f * H2D + 2 * p];
        const _Float16 b = (_Float16)W3[f * H2D + 2 * p + 1];
        U32H2 u;
        u.h[0] = a;
        u.h[1] = b;
        w3h[f * 64 + p] = u.u;
    }
}

// ---------------------------------------------------------------------------
// build_tables: one block per feature (128 threads = one lane per n).
// Sort breakpoints t_k = -b1/W1 (W1==0 -> +inf, delta 0). Interval walk
// builds A[i][n], C[i][n] prefix tables in f32, stored f16:
//   row i layout (u16): A[0..128) | C[0..128) | pad(2)  => 129 u32.
// A[0] = sum_{W1<0} W1*W2 ; C[0] = sum_{W1<0} b1*W2 + sum_{W1==0,b1>0} b1*W2
//        + b2[n] (b2 folded in). Crossing sorted entry k: dA=|W1| signed ON/OFF,
// dC=+-b1. Sorted t written to tsrt for the main kernel's binary search.
// ---------------------------------------------------------------------------
__global__ __launch_bounds__(128) void build_tables(
    const float* __restrict__ W1, const float* __restrict__ b1,
    const float* __restrict__ W2, const float* __restrict__ b2,
    _Float16* __restrict__ rows, float* __restrict__ tsrt) {
    __shared__ float t_s[256], w1_s[256], b1_s[256];
    __shared__ int id_s[256];
    const int f = blockIdx.x, tid = threadIdx.x;
#pragma unroll
    for (int k = tid; k < 256; k += 128) {
        w1_s[k] = W1[f * H1D + k];
        b1_s[k] = b1[f * H1D + k];
    }
    __syncthreads();
#pragma unroll
    for (int k = tid; k < 256; k += 128) {
        const float w = w1_s[k];
        t_s[k] = (w != 0.f) ? (-b1_s[k] / w) : __builtin_inff();
        id_s[k] = k;
    }
    __syncthreads();
    // bitonic sort (ascending by t), 256 elems, 128 threads = 1 pair each
    for (int k = 2; k <= 256; k <<= 1) {
        for (int j = k >> 1; j >= 1; j >>= 1) {
            const int i = 2 * tid - (tid & (j - 1));
            const int l = i + j;
            const bool up = ((i & k) == 0);
            const float ti = t_s[i], tl = t_s[l];
            const int ii = id_s[i], il = id_s[l];
            if (up ? (ti > tl) : (ti < tl)) {
                t_s[i] = tl; t_s[l] = ti;
                id_s[i] = il; id_s[l] = ii;
            }
            __syncthreads();
        }
    }
#pragma unroll
    for (int k = tid; k < 256; k += 128) tsrt[f * H1D + k] = t_s[k];

    const int n = tid;                       // 0..127
    const float* w2p = W2 + (size_t)f * H1D * H2D;
    float A = 0.f, C = b2[f * H2D + n];
#pragma unroll 8
    for (int k = 0; k < 256; ++k) {
        const float w = w1_s[k], bb = b1_s[k];
        const float w2 = w2p[k * H2D + n];
        if (w < 0.f) { A += w * w2; C += bb * w2; }
        else if (w == 0.f && bb > 0.f) C += bb * w2;
    }
    _Float16* rf = rows + (size_t)f * ROWS_PER_F * ROW_U16;
    rf[n] = (_Float16)A;
    rf[128 + n] = (_Float16)C;
#pragma unroll 16
    for (int i = 1; i <= 256; ++i) {
        const int kk = id_s[i - 1];
        const float w = w1_s[kk], bb = b1_s[kk];
        const float w2 = w2p[kk * H2D + n];
        const float dA = (w > 0.f) ? w : ((w < 0.f) ? -w : 0.f);
        const float dC = (w > 0.f) ? bb : ((w < 0.f) ? -bb : 0.f);
        A += dA * w2;
        C += dC * w2;
        rf[i * ROW_U16 + n] = (_Float16)A;
        rf[i * ROW_U16 + 128 + n] = (_Float16)C;
    }
}

// ---------------------------------------------------------------------------
// Main: one block per feature (256 blocks = 1/CU), 1024 threads (16 waves/CU).
// Stage the feature's 257x129-u32 table + 256 sorted t into dynamic LDS
// (133.6 KB). Per batch element (4 rounds x 1024 lanes): binary-search the
// interval c (9 guarded steps), then 64 x {2 ds_read_b32 (A-pair, C-pair;
// stride 129 => bank (c+nn)%32, conflict-light), pk_fma, pk_max, dot2-f32}.
// W3 pairs live in 64 per-lane registers (statically indexed).
// ---------------------------------------------------------------------------
__global__ __launch_bounds__(1024) void coxnam_main(
    const float* __restrict__ xT, const _Float16* __restrict__ rows,
    const float* __restrict__ tsrt, const unsigned* __restrict__ w3h,
    float* __restrict__ partial) {
    extern __shared__ unsigned lds[];
    unsigned* rlds = lds;                       // 33153 u32
    float* t_ls = (float*)(lds + LDS_U32);      // 256 f32
    const int f = blockIdx.x, tid = threadIdx.x;

    const unsigned* src = (const unsigned*)(rows + (size_t)f * ROWS_PER_F * ROW_U16);
    for (int i = tid; i < LDS_U32; i += 1024) rlds[i] = src[i];
    if (tid < 256) t_ls[tid] = tsrt[f * H1D + tid];

    unsigned w3r[64];
    const unsigned* wp = w3h + f * 64;
#pragma unroll
    for (int i = 0; i < 64; ++i) w3r[i] = wp[i];
    __syncthreads();

    const half2v z2 = {(_Float16)0.f, (_Float16)0.f};
    for (int rd = 0; rd < 4; ++rd) {
        const int b = rd * 1024 + tid;
        const float xv = xT[(size_t)f * BATCH + b];
        // rank = #{ t <= xv }  in [0,256]
        int c = 0;
#pragma unroll
        for (int s = 256; s >= 1; s >>= 1) {
            const int m = c + s;
            if (m <= 256 && t_ls[m - 1] <= xv) c = m;
        }
        const unsigned* rp = rlds + c * 129;
        half2v xv2;
        xv2[0] = (_Float16)xv;
        xv2[1] = xv2[0];
        float cacc = 0.f;
#pragma unroll
        for (int nn = 0; nn < 64; ++nn) {
            U32H2 a2, c2, w3;
            a2.u = rp[nn];
            c2.u = rp[64 + nn];
            w3.u = w3r[nn];
            const half2v h2 = xv2 * a2.h + c2.h;
            const half2v r = __builtin_elementwise_max(h2, z2);
#if __has_builtin(__builtin_amdgcn_fdot2)
            cacc = __builtin_amdgcn_fdot2(r, w3.h, cacc, false);
#else
            cacc += (float)r[0] * (float)w3.h[0] + (float)r[1] * (float)w3.h[1];
#endif
        }
        partial[(size_t)f * BATCH + b] = cacc;
    }
}

// ---------------------------------------------------------------------------
// Final reduction over 256 per-feature partials + sum of b3.
// ---------------------------------------------------------------------------
__global__ __launch_bounds__(256) void reduce_out(const float* __restrict__ partial,
                                                  const float* __restrict__ b3,
                                                  float* __restrict__ out) {
    const int b = blockIdx.x * 256 + threadIdx.x;
    float v = 0.f;
    for (int p = 0; p < FDIM; ++p) v += partial[(size_t)p * BATCH + b];
    float sb3 = 0.f;
#pragma unroll 4
    for (int f4 = 0; f4 < FDIM; f4 += 4) {
        const float4 t = *(const float4*)(b3 + f4);
        sb3 += t.x + t.y + t.z + t.w;
    }
    out[b] = v + sb3;
}

extern "C" void kernel_launch(void* const* d_in, const int* in_sizes, int n_in,
                              void* d_out, int out_size, void* d_ws, size_t ws_size,
                              hipStream_t stream) {
    const float* x  = (const float*)d_in[0];
    const float* W1 = (const float*)d_in[1];
    const float* b1 = (const float*)d_in[2];
    const float* W2 = (const float*)d_in[3];
    const float* b2 = (const float*)d_in[4];
    const float* W3 = (const float*)d_in[5];
    const float* b3 = (const float*)d_in[6];

    _Float16* rows  = (_Float16*)d_ws;
    float*    xT    = (float*)((char*)d_ws + ROWS_BYTES);
    float*    tsrt  = (float*)((char*)xT + XT_BYTES);
    unsigned* w3h   = (unsigned*)((char*)tsrt + TS_BYTES);
    float*    partial = (float*)((char*)w3h + W3H_BYTES);
    const size_t need = ROWS_BYTES + XT_BYTES + TS_BYTES + W3H_BYTES +
                        (size_t)BATCH * FDIM * 4;
    if (ws_size < need) return;  // insufficient scratch; fail visibly

    prep2<<<320, 256, 0, stream>>>(x, W3, xT, w3h);
    build_tables<<<256, 128, 0, stream>>>(W1, b1, W2, b2, rows, tsrt);
    coxnam_main<<<256, 1024, LDS_BYTES, stream>>>(xT, rows, tsrt, w3h, partial);
    reduce_out<<<BATCH / 256, 256, 0, stream>>>(partial, b3, (float*)d_out);
}

// Round 17
// 87.222 us; speedup vs baseline: 1.6293x; 1.6293x over previous
//
#include <hip/hip_runtime.h>

#define FDIM  256
#define H1D   256
#define H2D   128
#define BATCH 4096

typedef _Float16 half2v __attribute__((ext_vector_type(2)));

#define ROW_U16   258                       // 128 A + 128 C + 2 pad (129 u32)
#define ROWS_PER_F 257
#define ROWS_BYTES ((size_t)FDIM * ROWS_PER_F * ROW_U16 * 2)   // 33,948,672
#define XT_BYTES   ((size_t)FDIM * BATCH * 4)                  //  4,194,304
#define TS_BYTES   ((size_t)FDIM * H1D * 4)                    //    262,144
#define W3H_BYTES  ((size_t)FDIM * 64 * 4)                     //     65,536
#define LDS_U32    (ROWS_PER_F * 129)                          //     33,153
#define LDS_BYTES  (LDS_U32 * 4 + 256 * 4)                     //    133,636

#define SEG    8
#define SEGLEN 32                            // 256 / SEG

union U32H2 { unsigned u; half2v h; };

// ---------------------------------------------------------------------------
// prep2: [0,256): x (B,F) f32 -> xT (F,B) f32 transpose.
//        [256,320): W3 f32 -> f16-pair packed w3h[f][64].
// ---------------------------------------------------------------------------
__global__ __launch_bounds__(256) void prep2(const float* __restrict__ x,
                                             const float* __restrict__ W3,
                                             float* __restrict__ xT,
                                             unsigned* __restrict__ w3h) {
    const int bid = blockIdx.x, tid = threadIdx.x;
    if (bid < 256) {
        __shared__ float tile[64][65];
        const int bt = bid >> 2, ft = bid & 3;
        const int tr = tid >> 2, c0 = (tid & 3) * 16;
#pragma unroll
        for (int j = 0; j < 4; ++j) {
            const float4 v = *(const float4*)(
                x + (size_t)(bt * 64 + tr) * FDIM + ft * 64 + c0 + j * 4);
            tile[tr][c0 + j * 4 + 0] = v.x;
            tile[tr][c0 + j * 4 + 1] = v.y;
            tile[tr][c0 + j * 4 + 2] = v.z;
            tile[tr][c0 + j * 4 + 3] = v.w;
        }
        __syncthreads();
        const int fr = tid >> 2, bb = (tid & 3) * 16;
#pragma unroll
        for (int j = 0; j < 4; ++j) {
            float4 o;
            o.x = tile[bb + j * 4 + 0][fr];
            o.y = tile[bb + j * 4 + 1][fr];
            o.z = tile[bb + j * 4 + 2][fr];
            o.w = tile[bb + j * 4 + 3][fr];
            *(float4*)(xT + (size_t)(ft * 64 + fr) * BATCH + bt * 64 + bb + j * 4) = o;
        }
    } else {
        const int idx = (bid - 256) * 256 + tid;    // 0..16383
        const int f = idx >> 6, p = idx & 63;
        U32H2 u;
        u.h[0] = (_Float16)W3[f * H2D + 2 * p];
        u.h[1] = (_Float16)W3[f * H2D + 2 * p + 1];
        w3h[f * 64 + p] = u.u;
    }
}

// ---------------------------------------------------------------------------
// build_tables: one block per feature, 1024 threads = 8 segments x 128 n.
// Sort breakpoints t_k = -b1/W1 (W1==0 -> +inf, delta 0) via bitonic
// (128 active compare threads). Then a parallel scan over crossings:
//  Pass A: thread (seg,n) accumulates its 32-crossing segment's
//          dA/dC sums AND its 32-k share of the base A0/C0 reduction
//          (3 coalesced W2 loads per step). Barrier.
//  Offsets: base = sum BA/BC (+b2); off(seg) = base + sum_{s<seg} SA/SC.
//  Pass B: re-walk the segment from off, writing f16 rows (row i = state
//          after i crossings). Row 0 written by seg 0.
// ---------------------------------------------------------------------------
__global__ __launch_bounds__(1024) void build_tables(
    const float* __restrict__ W1, const float* __restrict__ b1,
    const float* __restrict__ W2, const float* __restrict__ b2,
    _Float16* __restrict__ rows, float* __restrict__ tsrt) {
    __shared__ float t_s[256], w1_s[256], b1_s[256];
    __shared__ int id_s[256];
    __shared__ float SA[SEG][128], SC[SEG][128], BA[SEG][128], BC[SEG][128];
    const int f = blockIdx.x, tid = threadIdx.x;

    if (tid < 256) {
        w1_s[tid] = W1[f * H1D + tid];
        b1_s[tid] = b1[f * H1D + tid];
    }
    __syncthreads();
    if (tid < 256) {
        const float w = w1_s[tid];
        t_s[tid] = (w != 0.f) ? (-b1_s[tid] / w) : __builtin_inff();
        id_s[tid] = tid;
    }
    __syncthreads();
    // bitonic sort (ascending by t), 256 elems, 128 compare threads
    for (int k = 2; k <= 256; k <<= 1) {
        for (int j = k >> 1; j >= 1; j >>= 1) {
            if (tid < 128) {
                const int i = 2 * tid - (tid & (j - 1));
                const int l = i + j;
                const bool up = ((i & k) == 0);
                const float ti = t_s[i], tl = t_s[l];
                const int ii = id_s[i], il = id_s[l];
                if (up ? (ti > tl) : (ti < tl)) {
                    t_s[i] = tl; t_s[l] = ti;
                    id_s[i] = il; id_s[l] = ii;
                }
            }
            __syncthreads();
        }
    }
    if (tid < 256) tsrt[f * H1D + tid] = t_s[tid];

    const int seg = tid >> 7, n = tid & 127;
    const float* w2p = W2 + (size_t)f * H1D * H2D;

    // ---- Pass A: segment delta sums + base partials ----
    {
        float sa = 0.f, sc = 0.f, ba = 0.f, bc = 0.f;
#pragma unroll 8
        for (int ii = 0; ii < SEGLEN; ++ii) {
            const int i = seg * SEGLEN + ii;
            // base partial (unsorted index i)
            const float w = w1_s[i], bb = b1_s[i];
            const float w2 = w2p[i * H2D + n];
            if (w < 0.f) { ba += w * w2; bc += bb * w2; }
            else if (w == 0.f && bb > 0.f) bc += bb * w2;
            // delta partial (sorted index)
            const int kk = id_s[i];
            const float ws = w1_s[kk], bs = b1_s[kk];
            const float w2s = w2p[kk * H2D + n];
            const float dA = (ws > 0.f) ? ws : ((ws < 0.f) ? -ws : 0.f);
            const float dC = (ws > 0.f) ? bs : ((ws < 0.f) ? -bs : 0.f);
            sa += dA * w2s;
            sc += dC * w2s;
        }
        SA[seg][n] = sa; SC[seg][n] = sc;
        BA[seg][n] = ba; BC[seg][n] = bc;
    }
    __syncthreads();

    // ---- offsets ----
    float baseA = 0.f, baseC = b2[f * H2D + n];
#pragma unroll
    for (int s = 0; s < SEG; ++s) { baseA += BA[s][n]; baseC += BC[s][n]; }
    float A = baseA, C = baseC;
    for (int s = 0; s < seg; ++s) { A += SA[s][n]; C += SC[s][n]; }

    _Float16* rf = rows + (size_t)f * ROWS_PER_F * ROW_U16;
    if (seg == 0) {
        rf[n] = (_Float16)baseA;
        rf[128 + n] = (_Float16)baseC;
    }

    // ---- Pass B: walk the segment, writing rows ----
#pragma unroll 8
    for (int ii = 0; ii < SEGLEN; ++ii) {
        const int i = seg * SEGLEN + ii + 1;      // row 1..256
        const int kk = id_s[i - 1];
        const float ws = w1_s[kk], bs = b1_s[kk];
        const float w2s = w2p[kk * H2D + n];
        const float dA = (ws > 0.f) ? ws : ((ws < 0.f) ? -ws : 0.f);
        const float dC = (ws > 0.f) ? bs : ((ws < 0.f) ? -bs : 0.f);
        A += dA * w2s;
        C += dC * w2s;
        rf[i * ROW_U16 + n] = (_Float16)A;
        rf[i * ROW_U16 + 128 + n] = (_Float16)C;
    }
}

// ---------------------------------------------------------------------------
// Main: one block per feature (256 blocks = 1/CU), 1024 threads. Stage the
// feature's 257x129-u32 table + 256 sorted t into dynamic LDS (133.6 KB).
// Per batch element: binary-search interval c, then 64 x {A,C pair reads
// (compiler-merged ds_read_b128), pk_fma, pk_max, fdot2}.
// ---------------------------------------------------------------------------
__global__ __launch_bounds__(1024) void coxnam_main(
    const float* __restrict__ xT, const _Float16* __restrict__ rows,
    const float* __restrict__ tsrt, const unsigned* __restrict__ w3h,
    float* __restrict__ partial) {
    extern __shared__ unsigned lds[];
    unsigned* rlds = lds;                       // 33153 u32
    float* t_ls = (float*)(lds + LDS_U32);      // 256 f32
    const int f = blockIdx.x, tid = threadIdx.x;

    const unsigned* src = (const unsigned*)(rows + (size_t)f * ROWS_PER_F * ROW_U16);
    for (int i = tid; i < LDS_U32; i += 1024) rlds[i] = src[i];
    if (tid < 256) t_ls[tid] = tsrt[f * H1D + tid];

    unsigned w3r[64];
    const unsigned* wp = w3h + f * 64;
#pragma unroll
    for (int i = 0; i < 64; ++i) w3r[i] = wp[i];
    __syncthreads();

    const half2v z2 = {(_Float16)0.f, (_Float16)0.f};
    for (int rd = 0; rd < 4; ++rd) {
        const int b = rd * 1024 + tid;
        const float xv = xT[(size_t)f * BATCH + b];
        int c = 0;
#pragma unroll
        for (int s = 256; s >= 1; s >>= 1) {
            const int m = c + s;
            if (m <= 256 && t_ls[m - 1] <= xv) c = m;
        }
        const unsigned* rp = rlds + c * 129;
        half2v xv2;
        xv2[0] = (_Float16)xv;
        xv2[1] = xv2[0];
        float cacc = 0.f;
#pragma unroll
        for (int nn = 0; nn < 64; ++nn) {
            U32H2 a2, c2, w3;
            a2.u = rp[nn];
            c2.u = rp[64 + nn];
            w3.u = w3r[nn];
            const half2v h2 = xv2 * a2.h + c2.h;
            const half2v r = __builtin_elementwise_max(h2, z2);
#if __has_builtin(__builtin_amdgcn_fdot2)
            cacc = __builtin_amdgcn_fdot2(r, w3.h, cacc, false);
#else
            cacc += (float)r[0] * (float)w3.h[0] + (float)r[1] * (float)w3.h[1];
#endif
        }
        partial[(size_t)f * BATCH + b] = cacc;
    }
}

// ---------------------------------------------------------------------------
// Final reduction over 256 per-feature partials + sum of b3.
// ---------------------------------------------------------------------------
__global__ __launch_bounds__(256) void reduce_out(const float* __restrict__ partial,
                                                  const float* __restrict__ b3,
                                                  float* __restrict__ out) {
    const int b = blockIdx.x * 256 + threadIdx.x;
    float v = 0.f;
    for (int p = 0; p < FDIM; ++p) v += partial[(size_t)p * BATCH + b];
    float sb3 = 0.f;
#pragma unroll 4
    for (int f4 = 0; f4 < FDIM; f4 += 4) {
        const float4 t = *(const float4*)(b3 + f4);
        sb3 += t.x + t.y + t.z + t.w;
    }
    out[b] = v + sb3;
}

extern "C" void kernel_launch(void* const* d_in, const int* in_sizes, int n_in,
                              void* d_out, int out_size, void* d_ws, size_t ws_size,
                              hipStream_t stream) {
    const float* x  = (const float*)d_in[0];
    const float* W1 = (const float*)d_in[1];
    const float* b1 = (const float*)d_in[2];
    const float* W2 = (const float*)d_in[3];
    const float* b2 = (const float*)d_in[4];
    const float* W3 = (const float*)d_in[5];
    const float* b3 = (const float*)d_in[6];

    _Float16* rows  = (_Float16*)d_ws;
    float*    xT    = (float*)((char*)d_ws + ROWS_BYTES);
    float*    tsrt  = (float*)((char*)xT + XT_BYTES);
    unsigned* w3h   = (unsigned*)((char*)tsrt + TS_BYTES);
    float*    partial = (float*)((char*)w3h + W3H_BYTES);
    const size_t need = ROWS_BYTES + XT_BYTES + TS_BYTES + W3H_BYTES +
                        (size_t)BATCH * FDIM * 4;
    if (ws_size < need) return;  // insufficient scratch; fail visibly

    prep2<<<320, 256, 0, stream>>>(x, W3, xT, w3h);
    build_tables<<<256, 1024, 0, stream>>>(W1, b1, W2, b2, rows, tsrt);
    coxnam_main<<<256, 1024, LDS_BYTES, stream>>>(xT, rows, tsrt, w3h, partial);
    reduce_out<<<BATCH / 256, 256, 0, stream>>>(partial, b3, (float*)d_out);
}

// Round 18
// 84.606 us; speedup vs baseline: 1.6797x; 1.0309x over previous
//
#include <hip/hip_runtime.h>

#define FDIM  256
#define H1D   256
#define H2D   128
#define BATCH 4096

typedef _Float16 half2v __attribute__((ext_vector_type(2)));

#define ROW_U32    130                       // 64 A-pairs + 64 C-pairs + 2 pad
#define NROWS      257
#define DLDS_U32   (NROWS * ROW_U32)         // 33,410
#define DLDS_BYTES (DLDS_U32 * 4)            // 133,640

#define XT_BYTES   ((size_t)FDIM * BATCH * 4)
#define W3H_BYTES  ((size_t)FDIM * 64 * 4)

#define SEG    8
#define SEGLEN 32

union U32H2 { unsigned u; half2v h; };

// ---------------------------------------------------------------------------
// prep2: [0,256): x (B,F) f32 -> xT (F,B) f32 transpose.
//        [256,320): W3 f32 -> f16-pair packed w3h[f][64].
// ---------------------------------------------------------------------------
__global__ __launch_bounds__(256) void prep2(const float* __restrict__ x,
                                             const float* __restrict__ W3,
                                             float* __restrict__ xT,
                                             unsigned* __restrict__ w3h) {
    const int bid = blockIdx.x, tid = threadIdx.x;
    if (bid < 256) {
        __shared__ float tile[64][65];
        const int bt = bid >> 2, ft = bid & 3;
        const int tr = tid >> 2, c0 = (tid & 3) * 16;
#pragma unroll
        for (int j = 0; j < 4; ++j) {
            const float4 v = *(const float4*)(
                x + (size_t)(bt * 64 + tr) * FDIM + ft * 64 + c0 + j * 4);
            tile[tr][c0 + j * 4 + 0] = v.x;
            tile[tr][c0 + j * 4 + 1] = v.y;
            tile[tr][c0 + j * 4 + 2] = v.z;
            tile[tr][c0 + j * 4 + 3] = v.w;
        }
        __syncthreads();
        const int fr = tid >> 2, bb = (tid & 3) * 16;
#pragma unroll
        for (int j = 0; j < 4; ++j) {
            float4 o;
            o.x = tile[bb + j * 4 + 0][fr];
            o.y = tile[bb + j * 4 + 1][fr];
            o.z = tile[bb + j * 4 + 2][fr];
            o.w = tile[bb + j * 4 + 3][fr];
            *(float4*)(xT + (size_t)(ft * 64 + fr) * BATCH + bt * 64 + bb + j * 4) = o;
        }
    } else {
        const int idx = (bid - 256) * 256 + tid;    // 0..16383
        const int f = idx >> 6, p = idx & 63;
        U32H2 u;
        u.h[0] = (_Float16)W3[f * H2D + 2 * p];
        u.h[1] = (_Float16)W3[f * H2D + 2 * p + 1];
        w3h[f * 64 + p] = u.u;
    }
}

// ---------------------------------------------------------------------------
// Fused build+eval: one block per feature (256 = 1/CU), 1024 threads.
// BUILD (into dynamic LDS, no global round-trip):
//   sort breakpoints t_k = -b1/W1 (bitonic, 128 compare threads) -> t_s;
//   Pass A (seg,n): 32-crossing delta sums + base partials; barrier;
//   Pass B: walk segment from its offset, writing f16 A/C rows into LDS.
//   Row layout (u32): [A-pair nn, C-pair nn] interleaved, stride 130 ->
//   inner loop reads merge to ds_read_b64, 8B-aligned.
// EVAL: per batch elem: binary-search interval c over t_s, then 64 x
//   {b64 (A,C) read, pk_fma, pk_max, fdot2}; W3 pairs are block-uniform
//   scalar loads (no VGPR array - 1024-thr kernel has 64-VGPR budget).
// ---------------------------------------------------------------------------
__global__ __launch_bounds__(1024) void coxnam_fused(
    const float* __restrict__ W1, const float* __restrict__ b1,
    const float* __restrict__ W2, const float* __restrict__ b2,
    const float* __restrict__ xT, const unsigned* __restrict__ w3h,
    float* __restrict__ partial) {
    extern __shared__ unsigned rlds[];          // 33,410 u32 = 130.5 KB
    __shared__ float t_s[256], w1_s[256], b1_s[256];
    __shared__ int id_s[256];
    __shared__ float SA[SEG][128], SC[SEG][128], BA[SEG][128], BC[SEG][128];
    const int f = blockIdx.x, tid = threadIdx.x;

    if (tid < 256) {
        w1_s[tid] = W1[f * H1D + tid];
        b1_s[tid] = b1[f * H1D + tid];
    }
    __syncthreads();
    if (tid < 256) {
        const float w = w1_s[tid];
        t_s[tid] = (w != 0.f) ? (-b1_s[tid] / w) : __builtin_inff();
        id_s[tid] = tid;
    }
    __syncthreads();
    // bitonic sort ascending by t (256 elems, 128 compare threads)
    for (int k = 2; k <= 256; k <<= 1) {
        for (int j = k >> 1; j >= 1; j >>= 1) {
            if (tid < 128) {
                const int i = 2 * tid - (tid & (j - 1));
                const int l = i + j;
                const bool up = ((i & k) == 0);
                const float ti = t_s[i], tl = t_s[l];
                const int ii = id_s[i], il = id_s[l];
                if (up ? (ti > tl) : (ti < tl)) {
                    t_s[i] = tl; t_s[l] = ti;
                    id_s[i] = il; id_s[l] = ii;
                }
            }
            __syncthreads();
        }
    }

    const int seg = tid >> 7, n = tid & 127;
    const float* w2p = W2 + (size_t)f * H1D * H2D;

    // ---- Pass A: segment delta sums + base partials ----
    {
        float sa = 0.f, sc = 0.f, ba = 0.f, bc = 0.f;
#pragma unroll 8
        for (int ii = 0; ii < SEGLEN; ++ii) {
            const int i = seg * SEGLEN + ii;
            const float w = w1_s[i], bb = b1_s[i];
            const float w2 = w2p[i * H2D + n];
            if (w < 0.f) { ba += w * w2; bc += bb * w2; }
            else if (w == 0.f && bb > 0.f) bc += bb * w2;
            const int kk = id_s[i];
            const float ws = w1_s[kk], bs = b1_s[kk];
            const float w2s = w2p[kk * H2D + n];
            const float dA = (ws > 0.f) ? ws : ((ws < 0.f) ? -ws : 0.f);
            const float dC = (ws > 0.f) ? bs : ((ws < 0.f) ? -bs : 0.f);
            sa += dA * w2s;
            sc += dC * w2s;
        }
        SA[seg][n] = sa; SC[seg][n] = sc;
        BA[seg][n] = ba; BC[seg][n] = bc;
    }
    __syncthreads();

    // ---- offsets + Pass B: write rows into dynamic LDS (f16) ----
    {
        float baseA = 0.f, baseC = b2[f * H2D + n];
#pragma unroll
        for (int s = 0; s < SEG; ++s) { baseA += BA[s][n]; baseC += BC[s][n]; }
        float A = baseA, C = baseC;
        for (int s = 0; s < seg; ++s) { A += SA[s][n]; C += SC[s][n]; }

        _Float16* rowh = (_Float16*)rlds;
        const int hbase = (n >> 1) * 4 + (n & 1);   // A half-slot; C = +2
        if (seg == 0) {
            rowh[hbase] = (_Float16)baseA;
            rowh[hbase + 2] = (_Float16)baseC;
        }
#pragma unroll 8
        for (int ii = 0; ii < SEGLEN; ++ii) {
            const int i = seg * SEGLEN + ii + 1;    // rows 1..256
            const int kk = id_s[i - 1];
            const float ws = w1_s[kk], bs = b1_s[kk];
            const float w2s = w2p[kk * H2D + n];
            const float dA = (ws > 0.f) ? ws : ((ws < 0.f) ? -ws : 0.f);
            const float dC = (ws > 0.f) ? bs : ((ws < 0.f) ? -bs : 0.f);
            A += dA * w2s;
            C += dC * w2s;
            rowh[i * (ROW_U32 * 2) + hbase] = (_Float16)A;
            rowh[i * (ROW_U32 * 2) + hbase + 2] = (_Float16)C;
        }
    }
    __syncthreads();

    // ---- EVAL phase ----
    const unsigned* wp = w3h + f * 64;
    const half2v z2 = {(_Float16)0.f, (_Float16)0.f};
    for (int rd = 0; rd < 4; ++rd) {
        const int b = rd * 1024 + tid;
        const float xv = xT[(size_t)f * BATCH + b];
        int c = 0;
#pragma unroll
        for (int s = 256; s >= 1; s >>= 1) {
            const int m = c + s;
            if (m <= 256 && t_s[m - 1] <= xv) c = m;
        }
        const unsigned* rp = rlds + c * ROW_U32;
        half2v xv2;
        xv2[0] = (_Float16)xv;
        xv2[1] = xv2[0];
        float cacc = 0.f;
#pragma unroll
        for (int nn = 0; nn < 64; ++nn) {
            U32H2 a2, c2, w3;
            a2.u = rp[2 * nn];
            c2.u = rp[2 * nn + 1];
            w3.u = wp[nn];
            const half2v h2 = xv2 * a2.h + c2.h;
            const half2v r = __builtin_elementwise_max(h2, z2);
#if __has_builtin(__builtin_amdgcn_fdot2)
            cacc = __builtin_amdgcn_fdot2(r, w3.h, cacc, false);
#else
            cacc += (float)r[0] * (float)w3.h[0] + (float)r[1] * (float)w3.h[1];
#endif
        }
        partial[(size_t)f * BATCH + b] = cacc;
    }
}

// ---------------------------------------------------------------------------
// Final reduction over 256 per-feature partials + sum of b3.
// ---------------------------------------------------------------------------
__global__ __launch_bounds__(256) void reduce_out(const float* __restrict__ partial,
                                                  const float* __restrict__ b3,
                                                  float* __restrict__ out) {
    const int b = blockIdx.x * 256 + threadIdx.x;
    float v = 0.f;
    for (int p = 0; p < FDIM; ++p) v += partial[(size_t)p * BATCH + b];
    float sb3 = 0.f;
#pragma unroll 4
    for (int f4 = 0; f4 < FDIM; f4 += 4) {
        const float4 t = *(const float4*)(b3 + f4);
        sb3 += t.x + t.y + t.z + t.w;
    }
    out[b] = v + sb3;
}

extern "C" void kernel_launch(void* const* d_in, const int* in_sizes, int n_in,
                              void* d_out, int out_size, void* d_ws, size_t ws_size,
                              hipStream_t stream) {
    const float* x  = (const float*)d_in[0];
    const float* W1 = (const float*)d_in[1];
    const float* b1 = (const float*)d_in[2];
    const float* W2 = (const float*)d_in[3];
    const float* b2 = (const float*)d_in[4];
    const float* W3 = (const float*)d_in[5];
    const float* b3 = (const float*)d_in[6];

    float*    xT      = (float*)d_ws;
    unsigned* w3h     = (unsigned*)((char*)xT + XT_BYTES);
    float*    partial = (float*)((char*)w3h + W3H_BYTES);
    const size_t need = XT_BYTES + W3H_BYTES + (size_t)FDIM * BATCH * 4;
    if (ws_size < need) return;  // insufficient scratch; fail visibly

    prep2<<<320, 256, 0, stream>>>(x, W3, xT, w3h);
    coxnam_fused<<<256, 1024, DLDS_BYTES, stream>>>(W1, b1, W2, b2, xT, w3h,
                                                    partial);
    reduce_out<<<BATCH / 256, 256, 0, stream>>>(partial, b3, (float*)d_out);
}

// Round 19
// 79.844 us; speedup vs baseline: 1.7799x; 1.0596x over previous
//
#include <hip/hip_runtime.h>

#define FDIM  256
#define H1D   256
#define H2D   128
#define BATCH 4096

typedef _Float16 half2v __attribute__((ext_vector_type(2)));

#define ROW_U32    130                       // 64 (A,C) u32 pairs interleaved + 2 pad
#define NROWS      257
#define DLDS_U32   (NROWS * ROW_U32)         // 33,410
#define DLDS_BYTES (DLDS_U32 * 4)            // 133,640

#define XT_BYTES   ((size_t)FDIM * BATCH * 4)
#define W3H_BYTES  ((size_t)FDIM * 64 * 4)

#define SEG    8
#define SEGLEN 32

union U32H2 { unsigned u; half2v h; };
union H16U { _Float16 h; unsigned short u; };

// ---------------------------------------------------------------------------
// prep2: [0,256): x (B,F) f32 -> xT (F,B) f32 transpose.
//        [256,320): W3 f32 -> f16-pair packed w3h[f][64].
// ---------------------------------------------------------------------------
__global__ __launch_bounds__(256) void prep2(const float* __restrict__ x,
                                             const float* __restrict__ W3,
                                             float* __restrict__ xT,
                                             unsigned* __restrict__ w3h) {
    const int bid = blockIdx.x, tid = threadIdx.x;
    if (bid < 256) {
        __shared__ float tile[64][65];
        const int bt = bid >> 2, ft = bid & 3;
        const int tr = tid >> 2, c0 = (tid & 3) * 16;
#pragma unroll
        for (int j = 0; j < 4; ++j) {
            const float4 v = *(const float4*)(
                x + (size_t)(bt * 64 + tr) * FDIM + ft * 64 + c0 + j * 4);
            tile[tr][c0 + j * 4 + 0] = v.x;
            tile[tr][c0 + j * 4 + 1] = v.y;
            tile[tr][c0 + j * 4 + 2] = v.z;
            tile[tr][c0 + j * 4 + 3] = v.w;
        }
        __syncthreads();
        const int fr = tid >> 2, bb = (tid & 3) * 16;
#pragma unroll
        for (int j = 0; j < 4; ++j) {
            float4 o;
            o.x = tile[bb + j * 4 + 0][fr];
            o.y = tile[bb + j * 4 + 1][fr];
            o.z = tile[bb + j * 4 + 2][fr];
            o.w = tile[bb + j * 4 + 3][fr];
            *(float4*)(xT + (size_t)(ft * 64 + fr) * BATCH + bt * 64 + bb + j * 4) = o;
        }
    } else {
        const int idx = (bid - 256) * 256 + tid;    // 0..16383
        const int f = idx >> 6, p = idx & 63;
        U32H2 u;
        u.h[0] = (_Float16)W3[f * H2D + 2 * p];
        u.h[1] = (_Float16)W3[f * H2D + 2 * p + 1];
        w3h[f * 64 + p] = u.u;
    }
}

// ---------------------------------------------------------------------------
// Fused build+eval: one block per feature (256 = 1/CU), 1024 threads.
// BUILD: bitonic-sort breakpoints; segmented scan (Pass A sums, Pass B walk)
//   writes f16 A/C rows into dynamic LDS. Pass B pairs adjacent lanes via
//   shfl_xor and stores ONE aligned uint2 per even lane: conflict-free.
// EVAL: E0: per-b binary search once; pack (c | f16(xv)<<16) into the 16 KB
//   scan-scratch (reused). E1: 16-lane groups share one b: lane gl reads
//   nn = q*16+gl -> the group's b64 reads cover all 16 pair-banks
//   DETERMINISTICALLY (structural 4-touch/bank floor, independent of c).
//   4-step shfl reduce; lane 0 writes.
// ---------------------------------------------------------------------------
__global__ __launch_bounds__(1024) void coxnam_fused(
    const float* __restrict__ W1, const float* __restrict__ b1,
    const float* __restrict__ W2, const float* __restrict__ b2,
    const float* __restrict__ xT, const unsigned* __restrict__ w3h,
    float* __restrict__ partial) {
    extern __shared__ unsigned rlds[];          // 33,410 u32 = 130.5 KB
    __shared__ float t_s[256], w1_s[256], b1_s[256];
    __shared__ int id_s[256];
    __shared__ unsigned scratch[SEG * 128 * 4]; // 16 KB: SA/SC/BA/BC, then c-pack
    float* SA = (float*)scratch;                // [SEG][128]
    float* SC = SA + SEG * 128;
    float* BA = SC + SEG * 128;
    float* BC = BA + SEG * 128;
    const int f = blockIdx.x, tid = threadIdx.x;

    if (tid < 256) {
        w1_s[tid] = W1[f * H1D + tid];
        b1_s[tid] = b1[f * H1D + tid];
    }
    __syncthreads();
    if (tid < 256) {
        const float w = w1_s[tid];
        t_s[tid] = (w != 0.f) ? (-b1_s[tid] / w) : __builtin_inff();
        id_s[tid] = tid;
    }
    __syncthreads();
    // bitonic sort ascending by t (256 elems, 128 compare threads)
    for (int k = 2; k <= 256; k <<= 1) {
        for (int j = k >> 1; j >= 1; j >>= 1) {
            if (tid < 128) {
                const int i = 2 * tid - (tid & (j - 1));
                const int l = i + j;
                const bool up = ((i & k) == 0);
                const float ti = t_s[i], tl = t_s[l];
                const int ii = id_s[i], il = id_s[l];
                if (up ? (ti > tl) : (ti < tl)) {
                    t_s[i] = tl; t_s[l] = ti;
                    id_s[i] = il; id_s[l] = ii;
                }
            }
            __syncthreads();
        }
    }

    const int seg = tid >> 7, n = tid & 127;
    const float* w2p = W2 + (size_t)f * H1D * H2D;

    // ---- Pass A: segment delta sums + base partials ----
    {
        float sa = 0.f, sc = 0.f, ba = 0.f, bc = 0.f;
#pragma unroll 8
        for (int ii = 0; ii < SEGLEN; ++ii) {
            const int i = seg * SEGLEN + ii;
            const float w = w1_s[i], bb = b1_s[i];
            const float w2 = w2p[i * H2D + n];
            if (w < 0.f) { ba += w * w2; bc += bb * w2; }
            else if (w == 0.f && bb > 0.f) bc += bb * w2;
            const int kk = id_s[i];
            const float ws = w1_s[kk], bs = b1_s[kk];
            const float w2s = w2p[kk * H2D + n];
            const float dA = (ws > 0.f) ? ws : ((ws < 0.f) ? -ws : 0.f);
            const float dC = (ws > 0.f) ? bs : ((ws < 0.f) ? -bs : 0.f);
            sa += dA * w2s;
            sc += dC * w2s;
        }
        SA[seg * 128 + n] = sa; SC[seg * 128 + n] = sc;
        BA[seg * 128 + n] = ba; BC[seg * 128 + n] = bc;
    }
    __syncthreads();

    // ---- offsets + Pass B: write interleaved (A,C) pair rows (uint2) ----
    {
        float baseA = 0.f, baseC = b2[f * H2D + n];
#pragma unroll
        for (int s = 0; s < SEG; ++s) {
            baseA += BA[s * 128 + n];
            baseC += BC[s * 128 + n];
        }
        float A = baseA, C = baseC;
        for (int s = 0; s < seg; ++s) {
            A += SA[s * 128 + n];
            C += SC[s * 128 + n];
        }
        const int pr = n >> 1;                    // pair index 0..63
        const bool wr = ((n & 1) == 0);
        // row 0 (seg 0 only)
        if (seg == 0) {
            H16U ah, ch;
            ah.h = (_Float16)baseA;
            ch.h = (_Float16)baseC;
            const unsigned ao = __shfl_xor((int)(unsigned)ah.u, 1);
            const unsigned co = __shfl_xor((int)(unsigned)ch.u, 1);
            if (wr) {
                uint2 v;
                v.x = (unsigned)ah.u | (ao << 16);
                v.y = (unsigned)ch.u | (co << 16);
                *(uint2*)(rlds + pr * 2) = v;
            }
        }
#pragma unroll 8
        for (int ii = 0; ii < SEGLEN; ++ii) {
            const int i = seg * SEGLEN + ii + 1;    // rows 1..256
            const int kk = id_s[i - 1];
            const float ws = w1_s[kk], bs = b1_s[kk];
            const float w2s = w2p[kk * H2D + n];
            const float dA = (ws > 0.f) ? ws : ((ws < 0.f) ? -ws : 0.f);
            const float dC = (ws > 0.f) ? bs : ((ws < 0.f) ? -bs : 0.f);
            A += dA * w2s;
            C += dC * w2s;
            H16U ah, ch;
            ah.h = (_Float16)A;
            ch.h = (_Float16)C;
            const unsigned ao = __shfl_xor((int)(unsigned)ah.u, 1);
            const unsigned co = __shfl_xor((int)(unsigned)ch.u, 1);
            if (wr) {
                uint2 v;
                v.x = (unsigned)ah.u | (ao << 16);
                v.y = (unsigned)ch.u | (co << 16);
                *(uint2*)(rlds + i * ROW_U32 + pr * 2) = v;
            }
        }
    }
    __syncthreads();

    // ---- E0: per-b interval search, pack (c | f16(xv)<<16) into scratch ----
#pragma unroll
    for (int rd = 0; rd < 4; ++rd) {
        const int b = rd * 1024 + tid;
        const float xv = xT[(size_t)f * BATCH + b];
        int c = 0;
#pragma unroll
        for (int s = 256; s >= 1; s >>= 1) {
            const int m = c + s;
            if (m <= 256 && t_s[m - 1] <= xv) c = m;
        }
        H16U hx;
        hx.h = (_Float16)xv;
        scratch[b] = (unsigned)c | ((unsigned)hx.u << 16);
    }
    __syncthreads();

    // ---- E1: 16-lane groups, structural conflict-free table reads ----
    const int grp = tid >> 4, gl = tid & 15;
    unsigned w3r[4];
    {
        const unsigned* wp = w3h + f * 64;
#pragma unroll
        for (int q = 0; q < 4; ++q) w3r[q] = wp[q * 16 + gl];
    }
    const half2v z2 = {(_Float16)0.f, (_Float16)0.f};
    for (int p = 0; p < 64; ++p) {
        const int b = p * 64 + grp;
        const unsigned cinfo = scratch[b];
        const unsigned c = cinfo & 0xffff;
        U32H2 xv2;
        xv2.u = (cinfo >> 16) | (cinfo & 0xffff0000u);
        const unsigned* rp = rlds + c * ROW_U32;
        float cacc = 0.f;
#pragma unroll
        for (int q = 0; q < 4; ++q) {
            const int nn = q * 16 + gl;
            const uint2 ac = *(const uint2*)(rp + 2 * nn);
            U32H2 a2, c2, w3u;
            a2.u = ac.x;
            c2.u = ac.y;
            w3u.u = w3r[q];
            const half2v h2 = xv2.h * a2.h + c2.h;
            const half2v r = __builtin_elementwise_max(h2, z2);
#if __has_builtin(__builtin_amdgcn_fdot2)
            cacc = __builtin_amdgcn_fdot2(r, w3u.h, cacc, false);
#else
            cacc += (float)r[0] * (float)w3u.h[0] + (float)r[1] * (float)w3u.h[1];
#endif
        }
        cacc += __shfl_xor(cacc, 1, 16);
        cacc += __shfl_xor(cacc, 2, 16);
        cacc += __shfl_xor(cacc, 4, 16);
        cacc += __shfl_xor(cacc, 8, 16);
        if (gl == 0) partial[(size_t)f * BATCH + b] = cacc;
    }
}

// ---------------------------------------------------------------------------
// Final reduction over 256 per-feature partials + sum of b3.
// ---------------------------------------------------------------------------
__global__ __launch_bounds__(256) void reduce_out(const float* __restrict__ partial,
                                                  const float* __restrict__ b3,
                                                  float* __restrict__ out) {
    const int b = blockIdx.x * 256 + threadIdx.x;
    float v = 0.f;
    for (int p = 0; p < FDIM; ++p) v += partial[(size_t)p * BATCH + b];
    float sb3 = 0.f;
#pragma unroll 4
    for (int f4 = 0; f4 < FDIM; f4 += 4) {
        const float4 t = *(const float4*)(b3 + f4);
        sb3 += t.x + t.y + t.z + t.w;
    }
    out[b] = v + sb3;
}

extern "C" void kernel_launch(void* const* d_in, const int* in_sizes, int n_in,
                              void* d_out, int out_size, void* d_ws, size_t ws_size,
                              hipStream_t stream) {
    const float* x  = (const float*)d_in[0];
    const float* W1 = (const float*)d_in[1];
    const float* b1 = (const float*)d_in[2];
    const float* W2 = (const float*)d_in[3];
    const float* b2 = (const float*)d_in[4];
    const float* W3 = (const float*)d_in[5];
    const float* b3 = (const float*)d_in[6];

    float*    xT      = (float*)d_ws;
    unsigned* w3h     = (unsigned*)((char*)xT + XT_BYTES);
    float*    partial = (float*)((char*)w3h + W3H_BYTES);
    const size_t need = XT_BYTES + W3H_BYTES + (size_t)FDIM * BATCH * 4;
    if (ws_size < need) return;  // insufficient scratch; fail visibly

    prep2<<<320, 256, 0, stream>>>(x, W3, xT, w3h);
    coxnam_fused<<<256, 1024, DLDS_BYTES, stream>>>(W1, b1, W2, b2, xT, w3h,
                                                    partial);
    reduce_out<<<BATCH / 256, 256, 0, stream>>>(partial, b3, (float*)d_out);
}

// Round 20
// 77.343 us; speedup vs baseline: 1.8374x; 1.0323x over previous
//
#include <hip/hip_runtime.h>

#define FDIM  256
#define H1D   256
#define H2D   128
#define BATCH 4096

typedef _Float16 half2v __attribute__((ext_vector_type(2)));

#define ROW_U32    132                       // 64 (A,C) u32 pairs + 4 pad (16B-aligned rows: 528 B)
#define NROWS      257
#define DLDS_U32   (NROWS * ROW_U32)         // 33,924
#define DLDS_BYTES (DLDS_U32 * 4)            // 135,696

#define XT_BYTES   ((size_t)FDIM * BATCH * 4)
#define W3H_BYTES  ((size_t)FDIM * 64 * 4)

#define SEG    8
#define SEGLEN 32

union U32H2 { unsigned u; half2v h; };
union H16U { _Float16 h; unsigned short u; };

// ---------------------------------------------------------------------------
// prep2: [0,256): x (B,F) f32 -> xT (F,B) f32 transpose.
//        [256,320): W3 f32 -> f16-pair packed w3h[f][64].
// ---------------------------------------------------------------------------
__global__ __launch_bounds__(256) void prep2(const float* __restrict__ x,
                                             const float* __restrict__ W3,
                                             float* __restrict__ xT,
                                             unsigned* __restrict__ w3h) {
    const int bid = blockIdx.x, tid = threadIdx.x;
    if (bid < 256) {
        __shared__ float tile[64][65];
        const int bt = bid >> 2, ft = bid & 3;
        const int tr = tid >> 2, c0 = (tid & 3) * 16;
#pragma unroll
        for (int j = 0; j < 4; ++j) {
            const float4 v = *(const float4*)(
                x + (size_t)(bt * 64 + tr) * FDIM + ft * 64 + c0 + j * 4);
            tile[tr][c0 + j * 4 + 0] = v.x;
            tile[tr][c0 + j * 4 + 1] = v.y;
            tile[tr][c0 + j * 4 + 2] = v.z;
            tile[tr][c0 + j * 4 + 3] = v.w;
        }
        __syncthreads();
        const int fr = tid >> 2, bb = (tid & 3) * 16;
#pragma unroll
        for (int j = 0; j < 4; ++j) {
            float4 o;
            o.x = tile[bb + j * 4 + 0][fr];
            o.y = tile[bb + j * 4 + 1][fr];
            o.z = tile[bb + j * 4 + 2][fr];
            o.w = tile[bb + j * 4 + 3][fr];
            *(float4*)(xT + (size_t)(ft * 64 + fr) * BATCH + bt * 64 + bb + j * 4) = o;
        }
    } else {
        const int idx = (bid - 256) * 256 + tid;    // 0..16383
        const int f = idx >> 6, p = idx & 63;
        U32H2 u;
        u.h[0] = (_Float16)W3[f * H2D + 2 * p];
        u.h[1] = (_Float16)W3[f * H2D + 2 * p + 1];
        w3h[f * 64 + p] = u.u;
    }
}

// ---------------------------------------------------------------------------
// Fused build+eval: one block per feature (256 = 1/CU), 1024 threads.
// BUILD:
//   RANK-SORT (3 barriers, no bitonic): 1024 threads compute partial ranks
//   (64 broadcast-read compares each), scatter ts2/id_s.
//   Pass A (sorted walk, base folded in - ONE W2 load/iter): segment delta
//   sums + base partials. Pass B: walk from offsets, shfl-paired uint2
//   writes of interleaved (A,C) f16-pair rows (stride 132 u32, 16B-aligned).
// EVAL:
//   E0: per-b binary search over ts2; pack (c | f16(xv)<<16) into scratch.
//   E1: 16-lane groups share one b; lane gl reads 2x uint4 (b128, pairs
//   {2gl+32q, +1}) - structural-floor LDS access independent of c; 2 fdot2
//   per uint4; 4-step shfl reduce.
// ---------------------------------------------------------------------------
__global__ __launch_bounds__(1024) void coxnam_fused(
    const float* __restrict__ W1, const float* __restrict__ b1,
    const float* __restrict__ W2, const float* __restrict__ b2,
    const float* __restrict__ xT, const unsigned* __restrict__ w3h,
    float* __restrict__ partial) {
    extern __shared__ unsigned rlds[];          // 33,924 u32 = 132.5 KB
    __shared__ float t_s[256], w1_s[256], b1_s[256], ts2[256];
    __shared__ int id_s[256];
    __shared__ unsigned scratch[SEG * 128 * 4]; // 16 KB: ranks / SA..BC / c-pack
    float* SA = (float*)scratch;                // [SEG][128]
    float* SC = SA + SEG * 128;
    float* BA = SC + SEG * 128;
    float* BC = BA + SEG * 128;
    const int f = blockIdx.x, tid = threadIdx.x;

    if (tid < 256) {
        const float w = W1[f * H1D + tid];
        const float bb = b1[f * H1D + tid];
        w1_s[tid] = w;
        b1_s[tid] = bb;
        t_s[tid] = (w != 0.f) ? (-bb / w) : __builtin_inff();
    }
    __syncthreads();

    // ---- rank-sort: partial ranks (broadcast reads), then scatter ----
    {
        const int kq = tid >> 8, kk = tid & 255;
        const float tk = t_s[kk];
        int r = 0;
        const int k0 = kq * 64;
#pragma unroll 16
        for (int k2 = k0; k2 < k0 + 64; ++k2) {
            const float t2 = t_s[k2];
            r += (t2 < tk || (t2 == tk && k2 < kk)) ? 1 : 0;
        }
        scratch[kq * 256 + kk] = (unsigned)r;
    }
    __syncthreads();
    if (tid < 256) {
        const int r = (int)(scratch[tid] + scratch[256 + tid] +
                            scratch[512 + tid] + scratch[768 + tid]);
        ts2[r] = t_s[tid];
        id_s[r] = tid;
    }
    __syncthreads();

    const int seg = tid >> 7, n = tid & 127;
    const float* w2p = W2 + (size_t)f * H1D * H2D;

    // ---- Pass A: sorted walk; delta sums + base partials, 1 load/iter ----
    {
        float sa = 0.f, sc = 0.f, ba = 0.f, bc = 0.f;
#pragma unroll 8
        for (int ii = 0; ii < SEGLEN; ++ii) {
            const int kk = id_s[seg * SEGLEN + ii];
            const float ws = w1_s[kk], bs = b1_s[kk];
            const float w2s = w2p[kk * H2D + n];
            if (ws < 0.f) { ba += ws * w2s; bc += bs * w2s; }
            else if (ws == 0.f && bs > 0.f) bc += bs * w2s;
            const float dA = (ws > 0.f) ? ws : ((ws < 0.f) ? -ws : 0.f);
            const float dC = (ws > 0.f) ? bs : ((ws < 0.f) ? -bs : 0.f);
            sa += dA * w2s;
            sc += dC * w2s;
        }
        SA[seg * 128 + n] = sa; SC[seg * 128 + n] = sc;
        BA[seg * 128 + n] = ba; BC[seg * 128 + n] = bc;
    }
    __syncthreads();

    // ---- offsets + Pass B: shfl-paired uint2 row writes ----
    {
        float baseA = 0.f, baseC = b2[f * H2D + n];
#pragma unroll
        for (int s = 0; s < SEG; ++s) {
            baseA += BA[s * 128 + n];
            baseC += BC[s * 128 + n];
        }
        float A = baseA, C = baseC;
        for (int s = 0; s < seg; ++s) {
            A += SA[s * 128 + n];
            C += SC[s * 128 + n];
        }
        const int pr = n >> 1;
        const bool wr = ((n & 1) == 0);
        if (seg == 0) {
            H16U ah, ch;
            ah.h = (_Float16)baseA;
            ch.h = (_Float16)baseC;
            const unsigned ao = __shfl_xor((int)(unsigned)ah.u, 1);
            const unsigned co = __shfl_xor((int)(unsigned)ch.u, 1);
            if (wr) {
                uint2 v;
                v.x = (unsigned)ah.u | (ao << 16);
                v.y = (unsigned)ch.u | (co << 16);
                *(uint2*)(rlds + pr * 2) = v;
            }
        }
#pragma unroll 8
        for (int ii = 0; ii < SEGLEN; ++ii) {
            const int i = seg * SEGLEN + ii + 1;    // rows 1..256
            const int kk = id_s[i - 1];
            const float ws = w1_s[kk], bs = b1_s[kk];
            const float w2s = w2p[kk * H2D + n];
            const float dA = (ws > 0.f) ? ws : ((ws < 0.f) ? -ws : 0.f);
            const float dC = (ws > 0.f) ? bs : ((ws < 0.f) ? -bs : 0.f);
            A += dA * w2s;
            C += dC * w2s;
            H16U ah, ch;
            ah.h = (_Float16)A;
            ch.h = (_Float16)C;
            const unsigned ao = __shfl_xor((int)(unsigned)ah.u, 1);
            const unsigned co = __shfl_xor((int)(unsigned)ch.u, 1);
            if (wr) {
                uint2 v;
                v.x = (unsigned)ah.u | (ao << 16);
                v.y = (unsigned)ch.u | (co << 16);
                *(uint2*)(rlds + i * ROW_U32 + pr * 2) = v;
            }
        }
    }
    __syncthreads();   // rows done; scratch (SA..BC) free for c-pack

    // ---- E0: per-b interval search, pack (c | f16(xv)<<16) ----
#pragma unroll
    for (int rd = 0; rd < 4; ++rd) {
        const int b = rd * 1024 + tid;
        const float xv = xT[(size_t)f * BATCH + b];
        int c = 0;
#pragma unroll
        for (int s = 256; s >= 1; s >>= 1) {
            const int m = c + s;
            if (m <= 256 && ts2[m - 1] <= xv) c = m;
        }
        H16U hx;
        hx.h = (_Float16)xv;
        scratch[b] = (unsigned)c | ((unsigned)hx.u << 16);
    }
    __syncthreads();

    // ---- E1: 16-lane groups, b128 structural-floor table reads ----
    const int grp = tid >> 4, gl = tid & 15;
    const unsigned* wp = w3h + f * 64;
    uint2 w3q0 = *(const uint2*)(wp + 2 * gl);
    uint2 w3q1 = *(const uint2*)(wp + 32 + 2 * gl);
    const half2v z2 = {(_Float16)0.f, (_Float16)0.f};
#pragma unroll 2
    for (int p = 0; p < 64; ++p) {
        const int b = p * 64 + grp;
        const unsigned cinfo = scratch[b];
        const unsigned c = cinfo & 0xffffu;
        U32H2 xv2;
        xv2.u = (cinfo >> 16) | (cinfo & 0xffff0000u);
        const unsigned* rp = rlds + c * ROW_U32;
        float cacc = 0.f;
#pragma unroll
        for (int q = 0; q < 2; ++q) {
            const uint4 v = *(const uint4*)(rp + 4 * gl + 64 * q);
            const uint2 wq = q ? w3q1 : w3q0;
            U32H2 a0, c0v, a1, c1v, w30, w31;
            a0.u = v.x; c0v.u = v.y; a1.u = v.z; c1v.u = v.w;
            w30.u = wq.x; w31.u = wq.y;
            half2v h0 = xv2.h * a0.h + c0v.h;
            half2v h1 = xv2.h * a1.h + c1v.h;
            h0 = __builtin_elementwise_max(h0, z2);
            h1 = __builtin_elementwise_max(h1, z2);
#if __has_builtin(__builtin_amdgcn_fdot2)
            cacc = __builtin_amdgcn_fdot2(h0, w30.h, cacc, false);
            cacc = __builtin_amdgcn_fdot2(h1, w31.h, cacc, false);
#else
            cacc += (float)h0[0] * (float)w30.h[0] + (float)h0[1] * (float)w30.h[1];
            cacc += (float)h1[0] * (float)w31.h[0] + (float)h1[1] * (float)w31.h[1];
#endif
        }
        cacc += __shfl_xor(cacc, 1, 16);
        cacc += __shfl_xor(cacc, 2, 16);
        cacc += __shfl_xor(cacc, 4, 16);
        cacc += __shfl_xor(cacc, 8, 16);
        if (gl == 0) partial[(size_t)f * BATCH + b] = cacc;
    }
}

// ---------------------------------------------------------------------------
// Final reduction over 256 per-feature partials + sum of b3.
// ---------------------------------------------------------------------------
__global__ __launch_bounds__(256) void reduce_out(const float* __restrict__ partial,
                                                  const float* __restrict__ b3,
                                                  float* __restrict__ out) {
    const int b = blockIdx.x * 256 + threadIdx.x;
    float v = 0.f;
    for (int p = 0; p < FDIM; ++p) v += partial[(size_t)p * BATCH + b];
    float sb3 = 0.f;
#pragma unroll 4
    for (int f4 = 0; f4 < FDIM; f4 += 4) {
        const float4 t = *(const float4*)(b3 + f4);
        sb3 += t.x + t.y + t.z + t.w;
    }
    out[b] = v + sb3;
}

extern "C" void kernel_launch(void* const* d_in, const int* in_sizes, int n_in,
                              void* d_out, int out_size, void* d_ws, size_t ws_size,
                              hipStream_t stream) {
    const float* x  = (const float*)d_in[0];
    const float* W1 = (const float*)d_in[1];
    const float* b1 = (const float*)d_in[2];
    const float* W2 = (const float*)d_in[3];
    const float* b2 = (const float*)d_in[4];
    const float* W3 = (const float*)d_in[5];
    const float* b3 = (const float*)d_in[6];

    float*    xT      = (float*)d_ws;
    unsigned* w3h     = (unsigned*)((char*)xT + XT_BYTES);
    float*    partial = (float*)((char*)w3h + W3H_BYTES);
    const size_t need = XT_BYTES + W3H_BYTES + (size_t)FDIM * BATCH * 4;
    if (ws_size < need) return;  // insufficient scratch; fail visibly

    prep2<<<320, 256, 0, stream>>>(x, W3, xT, w3h);
    coxnam_fused<<<256, 1024, DLDS_BYTES, stream>>>(W1, b1, W2, b2, xT, w3h,
                                                    partial);
    reduce_out<<<BATCH / 256, 256, 0, stream>>>(partial, b3, (float*)d_out);
}